// Round 1
// baseline (39796.118 us; speedup 1.0000x reference)
//
#include <hip/hip_runtime.h>
#include <math.h>

#define NN 1600
#define MAXD 500
#define TS 500
#define NBATCH 4
#define GBLK 200
#define RPB 8           // rows per block (4 waves * 2 rows)
#define DT 0.05f

// ---------------- workspace layout (floats) ----------------
// cnt   : [0       , 800000)   N*MAXD delay-count weights
// Hc    : [800000  , 1600000)  circular history, head h (logical d -> (h+d)%MAXD)
// dEbuf : [1600000 , 1603200)  double-buffered delayed_E (2 * N)
// bar   : at float offset 1603200, two ints 128B apart (count, gen)

__device__ __forceinline__ float h_tf_dev(float a, float b, float d, float c) {
    float u   = a * c - b;
    float num = 1e-5f + fabsf(u);
    float den = 1e-5f * d + fabsf(1.0f - expf(-d * u));
    return num / (den + 1e-8f);
}

__global__ void cnt_kernel(const int* __restrict__ delays, float* __restrict__ cnt) {
    __shared__ int hist[MAXD];
    const int i = blockIdx.x;
    for (int d = threadIdx.x; d < MAXD; d += blockDim.x) hist[d] = 0;
    __syncthreads();
    const int* row = delays + (size_t)i * NN;
    for (int j = threadIdx.x; j < NN; j += blockDim.x) atomicAdd(&hist[row[j]], 1);
    __syncthreads();
    for (int d = threadIdx.x; d < MAXD; d += blockDim.x)
        cnt[(size_t)i * MAXD + d] = (float)hist[d];
}

__global__ void init_kernel(const float* __restrict__ hE, const float* __restrict__ cnt,
                            float* __restrict__ Hc, float* __restrict__ dEbuf,
                            int* __restrict__ bar) {
    const int i = blockIdx.x;     // one wave per row
    const int lane = threadIdx.x; // 64 threads
    float s = 0.f;
    for (int d = lane; d < MAXD; d += 64) {
        float v = hE[(size_t)i * MAXD + d];
        Hc[(size_t)i * MAXD + d] = v;
        s = fmaf(cnt[(size_t)i * MAXD + d], v, s);
    }
    #pragma unroll
    for (int off = 32; off; off >>= 1) s += __shfl_xor(s, off);
    if (lane == 0) dEbuf[i] = s / 1600.0f;
    if (i == 0 && lane == 0) { bar[0] = 0; bar[32] = 0; }
}

__device__ __forceinline__ void grid_barrier(int* cnt_p, int* gen_p, int target) {
    __syncthreads();
    if (threadIdx.x == 0) {
        int prev = __hip_atomic_fetch_add(cnt_p, 1, __ATOMIC_ACQ_REL, __HIP_MEMORY_SCOPE_AGENT);
        if (prev == GBLK - 1) {
            __hip_atomic_store(cnt_p, 0, __ATOMIC_RELAXED, __HIP_MEMORY_SCOPE_AGENT);
            __hip_atomic_fetch_add(gen_p, 1, __ATOMIC_RELEASE, __HIP_MEMORY_SCOPE_AGENT);
        } else {
            while (__hip_atomic_load(gen_p, __ATOMIC_ACQUIRE, __HIP_MEMORY_SCOPE_AGENT) < target) {
                __builtin_amdgcn_s_sleep(2);
            }
        }
    }
    __syncthreads();
}

__global__ __launch_bounds__(256) void dmf_main(
        const float* __restrict__ x0, const float* __restrict__ L,
        const float* __restrict__ theta, const float* __restrict__ noise,
        float* __restrict__ out, const float* __restrict__ cnt,
        float* __restrict__ Hc, float* __restrict__ dEbuf, int* __restrict__ bar) {
    const int tid  = threadIdx.x;
    const int lane = tid & 63;
    const int wv   = tid >> 6;
    const int i0   = blockIdx.x * RPB + wv * 2;
    const int i1   = i0 + 1;

    const float std_in = theta[0],  W_E = theta[1],  tau_E = theta[2], gamma_E = theta[3];
    const float W_I = theta[4],     tau_I = theta[5], I_0 = theta[6],  g = theta[7];
    const float g_EE = theta[8],    g_IE = theta[9], g_EI = theta[10];
    const float aE = theta[11], bE = theta[12], dEc = theta[13];
    const float aI = theta[14], bI = theta[15], dIc = theta[16];
    const float sdt = std_in * sqrtf(DT);

    // carried state (valid in lane 0; computed there)
    float E0 = x0[i0 * 2 + 0], Iv0 = x0[i0 * 2 + 1];
    float E1 = x0[i1 * 2 + 0], Iv1 = x0[i1 * 2 + 1];

    const float* Lr0 = L + (size_t)i0 * NN;
    const float* Lr1 = L + (size_t)i1 * NN;
    const float* c0  = cnt + (size_t)i0 * MAXD;
    const float* c1  = cnt + (size_t)i1 * MAXD;
    float* H0 = Hc + (size_t)i0 * MAXD;
    float* H1 = Hc + (size_t)i1 * MAXD;

    int h = 0, cur = 0, target = 0;

    for (int b = 0; b < NBATCH; ++b) {
        const float n0E = noise[((size_t)b * NN + i0) * 2 + 0] * sdt;
        const float n0I = noise[((size_t)b * NN + i0) * 2 + 1] * sdt;
        const float n1E = noise[((size_t)b * NN + i1) * 2 + 0] * sdt;
        const float n1I = noise[((size_t)b * NN + i1) * 2 + 1] * sdt;

        if (lane == 0) {  // batch-start row of X = carried state
            size_t ro = ((size_t)b * TS) * (NN * 2);
            out[ro + i0 * 2 + 0] = E0; out[ro + i0 * 2 + 1] = Iv0;
            out[ro + i1 * 2 + 0] = E1; out[ro + i1 * 2 + 1] = Iv1;
        }

        for (int t = 1; t < TS; ++t) {
            // ---- phase 1: coupling = L @ delayed_E for 2 rows
            const float* de = dEbuf + (size_t)cur * NN;
            float p0 = 0.f, p1 = 0.f;
            #pragma unroll
            for (int k = 0; k < NN / 64; ++k) {
                int j = lane + k * 64;
                float d = de[j];
                p0 = fmaf(Lr0[j], d, p0);
                p1 = fmaf(Lr1[j], d, p1);
            }
            #pragma unroll
            for (int off = 32; off; off >>= 1) {
                p0 += __shfl_xor(p0, off);
                p1 += __shfl_xor(p1, off);
            }

            // ---- phase 2: pointwise update (lane 0), push history
            h = (h + MAXD - 1) % MAXD;  // uniform head update
            if (lane == 0) {
                size_t ro = ((size_t)b * TS + t) * (NN * 2);
                {
                    float E = E0, I = Iv0;
                    float IE = W_E * I_0 + g_EE * E + g * p0 - g_IE * I;
                    float II = W_I * I_0 + g_EI * E - I;
                    float RE = h_tf_dev(aE, bE, dEc, IE);
                    float RI = h_tf_dev(aI, bI, dIc, II);
                    float dE = -E / tau_E + (1.0f - E) * gamma_E * RE;
                    float dI = -I / tau_I + RI;
                    float En = E + DT * dE + n0E;
                    float In = I + DT * dI + n0I;
                    E0 = En; Iv0 = In;
                    out[ro + i0 * 2 + 0] = En; out[ro + i0 * 2 + 1] = In;
                    H0[h] = En;
                }
                {
                    float E = E1, I = Iv1;
                    float IE = W_E * I_0 + g_EE * E + g * p1 - g_IE * I;
                    float II = W_I * I_0 + g_EI * E - I;
                    float RE = h_tf_dev(aE, bE, dEc, IE);
                    float RI = h_tf_dev(aI, bI, dIc, II);
                    float dE = -E / tau_E + (1.0f - E) * gamma_E * RE;
                    float dI = -I / tau_I + RI;
                    float En = E + DT * dE + n1E;
                    float In = I + DT * dI + n1I;
                    E1 = En; Iv1 = In;
                    out[ro + i1 * 2 + 0] = En; out[ro + i1 * 2 + 1] = In;
                    H1[h] = En;
                }
            }
            __syncthreads();  // make H pushes visible to all lanes

            // ---- phase 3: delayed_E for NEXT step (own rows only)
            float s0 = 0.f, s1 = 0.f;
            for (int d = lane; d < MAXD; d += 64) {
                int hd = h + d; if (hd >= MAXD) hd -= MAXD;
                s0 = fmaf(c0[d], H0[hd], s0);
                s1 = fmaf(c1[d], H1[hd], s1);
            }
            #pragma unroll
            for (int off = 32; off; off >>= 1) {
                s0 += __shfl_xor(s0, off);
                s1 += __shfl_xor(s1, off);
            }
            if (lane == 0) {
                dEbuf[(size_t)(cur ^ 1) * NN + i0] = s0 / 1600.0f;
                dEbuf[(size_t)(cur ^ 1) * NN + i1] = s1 / 1600.0f;
            }

            ++target;
            grid_barrier(bar, bar + 32, target);
            cur ^= 1;
        }
    }

    // ---- finals: x_f then hE_f (logical order from circular buffer)
    const size_t xo = (size_t)(NBATCH * TS) * NN * 2;
    if (lane == 0) {
        out[xo + i0 * 2 + 0] = E0; out[xo + i0 * 2 + 1] = Iv0;
        out[xo + i1 * 2 + 0] = E1; out[xo + i1 * 2 + 1] = Iv1;
    }
    const size_t ho = xo + NN * 2;
    for (int d = lane; d < MAXD; d += 64) {
        int hd = h + d; if (hd >= MAXD) hd -= MAXD;
        out[ho + (size_t)i0 * MAXD + d] = H0[hd];
        out[ho + (size_t)i1 * MAXD + d] = H1[hd];
    }
}

extern "C" void kernel_launch(void* const* d_in, const int* in_sizes, int n_in,
                              void* d_out, int out_size, void* d_ws, size_t ws_size,
                              hipStream_t stream) {
    const float* x0     = (const float*)d_in[0];
    const float* hE     = (const float*)d_in[1];
    const float* L      = (const float*)d_in[2];
    const float* theta  = (const float*)d_in[3];
    const float* noise  = (const float*)d_in[4];
    const int*   delays = (const int*)d_in[5];
    float* out = (float*)d_out;

    float* ws    = (float*)d_ws;
    float* cnt   = ws;
    float* Hc    = ws + 800000;
    float* dEbuf = ws + 1600000;
    int*   bar   = (int*)(ws + 1603200);

    cnt_kernel<<<NN, 256, 0, stream>>>(delays, cnt);
    init_kernel<<<NN, 64, 0, stream>>>(hE, cnt, Hc, dEbuf, bar);
    dmf_main<<<GBLK, 256, 0, stream>>>(x0, L, theta, noise, out, cnt, Hc, dEbuf, bar);
}

// Round 2
// 10059.074 us; speedup vs baseline: 3.9562x; 3.9562x over previous
//
#include <hip/hip_runtime.h>
#include <math.h>

#define NN 1600
#define MAXD 500
#define TS 500
#define NBATCH 4
#define GBLK 50
#define WAVES 4
#define RPW 8                 // rows per wave
#define RPB (WAVES * RPW)     // 32 rows per block
#define DT 0.05f
#define FLAG_STRIDE 16        // ints -> 64B per flag line

// ---------------- workspace layout (floats) ----------------
// cnt   : [0       , 800000)   N*MAXD delay-count weights
// Hc    : [800000  , 1600000)  circular history, head h (logical d -> (h+d)%MAXD)
// dEbuf : [1600000 , 1603200)  double-buffered delayed_E (2 * N)
// flags : at float offset 1603200, GBLK ints, 64B apart

#define AT_LOADF(p)   __hip_atomic_load((p), __ATOMIC_RELAXED, __HIP_MEMORY_SCOPE_AGENT)
#define AT_STOREF(p,v) __hip_atomic_store((p), (v), __ATOMIC_RELAXED, __HIP_MEMORY_SCOPE_AGENT)
#define AT_LOADI(p)   __hip_atomic_load((p), __ATOMIC_RELAXED, __HIP_MEMORY_SCOPE_AGENT)
#define AT_STOREI(p,v) __hip_atomic_store((p), (v), __ATOMIC_RELAXED, __HIP_MEMORY_SCOPE_AGENT)

__device__ __forceinline__ float h_tf_dev(float a, float b, float d, float c) {
    float u   = a * c - b;
    float num = 1e-5f + fabsf(u);
    float den = 1e-5f * d + fabsf(1.0f - expf(-d * u));
    return num / (den + 1e-8f);
}

__global__ void cnt_kernel(const int* __restrict__ delays, float* __restrict__ cnt) {
    __shared__ int hist[MAXD];
    const int i = blockIdx.x;
    for (int d = threadIdx.x; d < MAXD; d += blockDim.x) hist[d] = 0;
    __syncthreads();
    const int* row = delays + (size_t)i * NN;
    for (int j = threadIdx.x; j < NN; j += blockDim.x) atomicAdd(&hist[row[j]], 1);
    __syncthreads();
    for (int d = threadIdx.x; d < MAXD; d += blockDim.x)
        cnt[(size_t)i * MAXD + d] = (float)hist[d];
}

__global__ void init_kernel(const float* __restrict__ hE, const float* __restrict__ cnt,
                            float* __restrict__ Hc, float* __restrict__ dEbuf,
                            int* __restrict__ flags) {
    const int i = blockIdx.x;     // one wave per row
    const int lane = threadIdx.x; // 64 threads
    float s = 0.f;
    for (int d = lane; d < MAXD; d += 64) {
        float v = hE[(size_t)i * MAXD + d];
        Hc[(size_t)i * MAXD + d] = v;
        s = fmaf(cnt[(size_t)i * MAXD + d], v, s);
    }
    #pragma unroll
    for (int off = 32; off; off >>= 1) s += __shfl_xor(s, off);
    if (lane == 0) dEbuf[i] = s / 1600.0f;
    if (i == 0) {
        for (int k = lane; k < GBLK * FLAG_STRIDE; k += 64) flags[k] = 0;
    }
}

__global__ __launch_bounds__(256) void dmf_main(
        const float* __restrict__ x0, const float* __restrict__ L,
        const float* __restrict__ theta, const float* __restrict__ noise,
        float* __restrict__ out, const float* __restrict__ cnt,
        float* __restrict__ Hc, float* dEbuf, int* flags) {
    const int tid  = threadIdx.x;
    const int lane = tid & 63;
    const int wv   = tid >> 6;
    const int base = blockIdx.x * RPB + wv * RPW;   // first row of this wave

    const float std_in = theta[0],  W_E = theta[1],  tau_E = theta[2], gamma_E = theta[3];
    const float W_I = theta[4],     tau_I = theta[5], I_0 = theta[6],  g = theta[7];
    const float g_EE = theta[8],    g_IE = theta[9], g_EI = theta[10];
    const float aE = theta[11], bE = theta[12], dEc = theta[13];
    const float aI = theta[14], bI = theta[15], dIc = theta[16];
    const float sdt = std_in * sqrtf(DT);

    // lane r (r < RPW) owns row base+r: state E,I held in that lane
    float E = 0.f, I = 0.f, cnt0 = 0.f;
    float* Hmy = Hc;    // valid for lane<RPW
    if (lane < RPW) {
        const int i = base + lane;
        E = x0[i * 2 + 0];
        I = x0[i * 2 + 1];
        cnt0 = cnt[(size_t)i * MAXD + 0];
        Hmy = Hc + (size_t)i * MAXD;
    }

    // row pointers (uniform per wave)
    const float* Lr[RPW];
    const float* Hr[RPW];
    #pragma unroll
    for (int r = 0; r < RPW; ++r) {
        Lr[r] = L  + (size_t)(base + r) * NN;
        Hr[r] = Hc + (size_t)(base + r) * MAXD;
    }

    // preload delay-count weights into registers (fixed for whole run)
    float creg[8][RPW];
    #pragma unroll
    for (int k = 0; k < 8; ++k) {
        const int d = lane + k * 64;
        #pragma unroll
        for (int r = 0; r < RPW; ++r)
            creg[k][r] = (d < MAXD) ? cnt[(size_t)(base + r) * MAXD + d] : 0.f;
    }

    __shared__ float xout[RPB * 2];

    int h = 0, cur = 0, target = 0;

    for (int b = 0; b < NBATCH; ++b) {
        float nE = 0.f, nI = 0.f;
        if (lane < RPW) {
            const int i = base + lane;
            nE = noise[((size_t)b * NN + i) * 2 + 0] * sdt;
            nI = noise[((size_t)b * NN + i) * 2 + 1] * sdt;
            // batch-start row of X = carried state
            size_t ro = ((size_t)b * TS) * (NN * 2);
            out[ro + i * 2 + 0] = E;
            out[ro + i * 2 + 1] = I;
        }

        for (int t = 1; t < TS; ++t) {
            h = (h == 0) ? (MAXD - 1) : (h - 1);   // new head (uniform)

            // ---- phase 1: coupling matvec over coherent exchange vector
            float* de = dEbuf + (size_t)cur * NN;
            float p[RPW];
            float s[RPW];
            #pragma unroll
            for (int r = 0; r < RPW; ++r) { p[r] = 0.f; s[r] = 0.f; }

            #pragma unroll
            for (int k = 0; k < NN / 64; ++k) {
                const int j = lane + k * 64;
                const float dv = AT_LOADF(&de[j]);
                #pragma unroll
                for (int r = 0; r < RPW; ++r) p[r] = fmaf(Lr[r][j], dv, p[r]);
            }

            // ---- phase 1b (fused): delayed-sum over OLD history (d >= 1)
            #pragma unroll
            for (int k = 0; k < 8; ++k) {
                const int d = lane + k * 64;
                if (d >= 1 && d < MAXD) {
                    int hd = h + d; if (hd >= MAXD) hd -= MAXD;
                    #pragma unroll
                    for (int r = 0; r < RPW; ++r) s[r] = fmaf(creg[k][r], Hr[r][hd], s[r]);
                }
            }

            // ---- butterfly reduce all 16 values across the wave
            #pragma unroll
            for (int off = 32; off; off >>= 1) {
                #pragma unroll
                for (int r = 0; r < RPW; ++r) {
                    p[r] += __shfl_xor(p[r], off);
                    s[r] += __shfl_xor(s[r], off);
                }
            }
            // static select: lane r takes element r (no runtime indexing -> no scratch)
            float pv = p[0], sv = s[0];
            #pragma unroll
            for (int r = 1; r < RPW; ++r) {
                pv = (lane == r) ? p[r] : pv;
                sv = (lane == r) ? s[r] : sv;
            }

            // ---- phase 2: per-row update in lane r
            if (lane < RPW) {
                const float IE = W_E * I_0 + g_EE * E + g * pv - g_IE * I;
                const float II = W_I * I_0 + g_EI * E - I;
                const float RE = h_tf_dev(aE, bE, dEc, IE);
                const float RI = h_tf_dev(aI, bI, dIc, II);
                const float dEd = -E / tau_E + (1.0f - E) * gamma_E * RE;
                const float dId = -I / tau_I + RI;
                E = E + DT * dEd + nE;
                I = I + DT * dId + nI;
                Hmy[h] = E;                                   // push history
                xout[(wv * RPW + lane) * 2 + 0] = E;          // stage X row
                xout[(wv * RPW + lane) * 2 + 1] = I;
                const float sfin = sv + cnt0 * E;             // add d=0 term
                AT_STOREF(&dEbuf[(size_t)(cur ^ 1) * NN + base + lane], sfin * (1.0f / 1600.0f));
            }

            __syncthreads();  // drains all waves' dEbuf stores + xout + H pushes

            // coalesced X write: wave 0 writes the block's 64 contiguous floats
            if (wv == 0) {
                size_t ro = ((size_t)b * TS + t) * (NN * 2);
                out[ro + (size_t)blockIdx.x * (RPB * 2) + lane] = xout[lane];
            }

            // publish step completion on our own cache line
            ++target;
            if (tid == 0) AT_STOREI(&flags[blockIdx.x * FLAG_STRIDE], target);

            // wave 0 polls all flags in parallel (one lane per block)
            if (wv == 0) {
                for (;;) {
                    int v = (lane < GBLK) ? AT_LOADI(&flags[lane * FLAG_STRIDE]) : target;
                    if (__all(v >= target)) break;
                    __builtin_amdgcn_s_sleep(1);
                }
            }
            __syncthreads();
            cur ^= 1;
        }
    }

    // ---- finals: x_f then hE_f (logical order from circular buffer)
    const size_t xo = (size_t)(NBATCH * TS) * NN * 2;
    if (lane < RPW) {
        const int i = base + lane;
        out[xo + i * 2 + 0] = E;
        out[xo + i * 2 + 1] = I;
    }
    const size_t ho = xo + NN * 2;
    #pragma unroll
    for (int k = 0; k < 8; ++k) {
        const int d = lane + k * 64;
        if (d < MAXD) {
            int hd = h + d; if (hd >= MAXD) hd -= MAXD;
            #pragma unroll
            for (int r = 0; r < RPW; ++r)
                out[ho + (size_t)(base + r) * MAXD + d] = Hr[r][hd];
        }
    }
}

extern "C" void kernel_launch(void* const* d_in, const int* in_sizes, int n_in,
                              void* d_out, int out_size, void* d_ws, size_t ws_size,
                              hipStream_t stream) {
    const float* x0     = (const float*)d_in[0];
    const float* hE     = (const float*)d_in[1];
    const float* L      = (const float*)d_in[2];
    const float* theta  = (const float*)d_in[3];
    const float* noise  = (const float*)d_in[4];
    const int*   delays = (const int*)d_in[5];
    float* out = (float*)d_out;

    float* ws    = (float*)d_ws;
    float* cnt   = ws;
    float* Hc    = ws + 800000;
    float* dEbuf = ws + 1600000;
    int*   flags = (int*)(ws + 1603200);

    cnt_kernel<<<NN, 256, 0, stream>>>(delays, cnt);
    init_kernel<<<NN, 64, 0, stream>>>(hE, cnt, Hc, dEbuf, flags);
    dmf_main<<<GBLK, 256, 0, stream>>>(x0, L, theta, noise, out, cnt, Hc, dEbuf, flags);
}